// Round 1
// baseline (73.288 us; speedup 1.0000x reference)
//
#include <hip/hip_runtime.h>
#include <math.h>

#define GRID   80
#define NT     50     // targets per image
#define C5     85     // 80 classes + 5
#define BATCH  64
#define TPB    256
#define CELLS_PER_IMG (GRID*GRID)          // 6400
#define BLKS_PER_IMG  (CELLS_PER_IMG/TPB)  // 25

// numerically-stable softplus, matches jax.nn.softplus = max(x,0)+log1p(exp(-|x|))
__device__ __forceinline__ float sp(float x) {
    return fmaxf(x, 0.0f) + log1pf(expf(-fabsf(x)));
}

// ws accumulators: [0]=obj_sum  [1]=coord_raw_sum  [2]=class_sum  [3]=noobj_raw_sum

// One 64-lane wave per target. Lanes cover channels {lane, lane+64}.
__global__ void target_kernel(const float* __restrict__ pred,
                              const float* __restrict__ tgt,
                              float* __restrict__ acc) {
    const int wid  = (blockIdx.x * blockDim.x + threadIdx.x) >> 6; // global wave id = target id
    const int lane = threadIdx.x & 63;
    const int nT   = BATCH * NT;

    float obj = 0.0f, coord = 0.0f, cls = 0.0f;

    if (wid < nT) {
        const int b = wid / NT;
        const int t = wid - b * NT;
        const float* tp = tgt + ((size_t)b * NT + t) * 5;
        const float t0 = tp[0], t1 = tp[1], t2 = tp[2], t3 = tp[3], t4 = tp[4];
        const int   cid = (int)t0;                 // already floored by setup
        const float xg = t1 * GRID, yg = t2 * GRID;
        const float wg = t3 * GRID, hg = t4 * GRID;
        const int gx = min(max((int)xg, 0), GRID - 1);
        const int gy = min(max((int)yg, 0), GRID - 1);
        const float xt = xg - (float)gx;
        const float yt = yg - (float)gy;
        const float* pp = pred + (((size_t)b * GRID + gy) * GRID + gx) * C5;

        // channel = lane (0..63)
        {
            const int c = lane;
            const float p = pp[c];
            if (c == 0) {
                obj = sp(-p);
            } else if (c == 1) {
                const float s = 1.0f / (1.0f + expf(-p));
                const float d = s - xt; coord = d * d;
            } else if (c == 2) {
                const float s = 1.0f / (1.0f + expf(-p));
                const float d = s - yt; coord = d * d;
            } else if (c == 3) {
                const float d = p - wg; coord = d * d;
            } else if (c == 4) {
                const float d = p - hg; coord = d * d;
            } else {
                cls = sp(p) - ((c - 5) == cid ? p : 0.0f);
            }
        }
        // channel = lane + 64 (64..84)
        const int c2 = lane + 64;
        if (c2 < C5) {
            const float p = pp[c2];
            cls += sp(p) - ((c2 - 5) == cid ? p : 0.0f);
        }
    }

    // wave reduce all three
    #pragma unroll
    for (int off = 32; off; off >>= 1) {
        obj   += __shfl_xor(obj,   off);
        coord += __shfl_xor(coord, off);
        cls   += __shfl_xor(cls,   off);
    }

    __shared__ float s_o[4], s_c[4], s_k[4];
    const int w = threadIdx.x >> 6;
    if (lane == 0) { s_o[w] = obj; s_c[w] = coord; s_k[w] = cls; }
    __syncthreads();
    if (threadIdx.x == 0) {
        float o = 0, c = 0, k = 0;
        #pragma unroll
        for (int i = 0; i < 4; ++i) { o += s_o[i]; c += s_c[i]; k += s_k[i]; }
        atomicAdd(&acc[0], o);
        atomicAdd(&acc[1], c);
        atomicAdd(&acc[2], k);
    }
}

// One block = 256 cells of one image. Occupancy test vs 50 LDS-resident target cells.
__global__ void noobj_kernel(const float* __restrict__ pred,
                             const float* __restrict__ tgt,
                             float* __restrict__ acc) {
    __shared__ int s_occ[NT];
    const int b   = blockIdx.x / BLKS_PER_IMG;
    const int blk = blockIdx.x % BLKS_PER_IMG;
    const int tid = threadIdx.x;

    if (tid < NT) {
        const float* tp = tgt + ((size_t)b * NT + tid) * 5;
        const int tx = (int)(tp[1] * GRID);   // unclipped, as in reference
        const int ty = (int)(tp[2] * GRID);
        s_occ[tid] = ty * GRID + tx;
    }
    __syncthreads();

    const int ci = blk * TPB + tid;           // 0..6399 within image
    const float p0 = pred[((size_t)b * CELLS_PER_IMG + ci) * C5];

    bool occ = false;
    #pragma unroll
    for (int t = 0; t < NT; ++t) occ |= (s_occ[t] == ci);

    float v = occ ? 0.0f : sp(p0);

    #pragma unroll
    for (int off = 32; off; off >>= 1) v += __shfl_xor(v, off);

    __shared__ float s_v[4];
    const int lane = tid & 63, w = tid >> 6;
    if (lane == 0) s_v[w] = v;
    __syncthreads();
    if (tid == 0) atomicAdd(&acc[3], s_v[0] + s_v[1] + s_v[2] + s_v[3]);
}

__global__ void finalize_kernel(const float* __restrict__ acc, float* __restrict__ out) {
    if (threadIdx.x == 0 && blockIdx.x == 0) {
        const float invB  = 1.0f / (float)BATCH;
        const float obj   = acc[0] * invB;
        const float coord = 5.0f * acc[1] * invB;
        const float cls   = acc[2] * invB;
        const float noobj = 0.5f * acc[3] * invB;
        out[0] = obj + noobj + coord + cls;
        out[1] = obj;
        out[2] = noobj;
        out[3] = coord;
        out[4] = cls;
    }
}

extern "C" void kernel_launch(void* const* d_in, const int* in_sizes, int n_in,
                              void* d_out, int out_size, void* d_ws, size_t ws_size,
                              hipStream_t stream) {
    const float* pred = (const float*)d_in[0];
    const float* tgt  = (const float*)d_in[1];
    float* acc = (float*)d_ws;
    float* out = (float*)d_out;

    hipMemsetAsync(d_ws, 0, 4 * sizeof(float), stream);

    // 3200 targets, one wave each -> 3200*64 threads -> 800 blocks of 256
    const int nWaveThreads = BATCH * NT * 64;
    target_kernel<<<(nWaveThreads + TPB - 1) / TPB, TPB, 0, stream>>>(pred, tgt, acc);

    // 64 images * 25 blocks each
    noobj_kernel<<<BATCH * BLKS_PER_IMG, TPB, 0, stream>>>(pred, tgt, acc);

    finalize_kernel<<<1, 64, 0, stream>>>(acc, out);
}

// Round 2
// 19.295 us; speedup vs baseline: 3.7983x; 3.7983x over previous
//
#include <hip/hip_runtime.h>
#include <math.h>

#define GRID_SZ 80
#define NT      50            // targets per image
#define C5      85            // 80 classes + 5
#define BATCH   64
#define TPB     256
#define CELLS   (GRID_SZ*GRID_SZ)       // 6400
#define BLKS_PER_IMG (CELLS/TPB)        // 25
#define NBLK    (BATCH*BLKS_PER_IMG)    // 1600

// numerically-stable softplus, matches jax.nn.softplus = max(x,0)+log1p(exp(-|x|))
__device__ __forceinline__ float sp(float x) {
    return fmaxf(x, 0.0f) + log1pf(expf(-fabsf(x)));
}

// d_ws layout: partials[NBLK][4] = {obj, coord_raw, class, noobj_raw} per block.
// Every block writes its 4 floats unconditionally -> no init / memset needed.

__global__ __launch_bounds__(TPB) void main_kernel(const float* __restrict__ pred,
                                                   const float* __restrict__ tgt,
                                                   float* __restrict__ partials) {
    const int tid  = threadIdx.x;
    const int lane = tid & 63;
    const int w    = tid >> 6;
    const int b    = blockIdx.x / BLKS_PER_IMG;   // image for noobj slice
    const int blk  = blockIdx.x % BLKS_PER_IMG;   // 256-cell chunk within image

    __shared__ unsigned s_bits[TPB / 32];   // occupancy bitmap for this block's 256 cells
    __shared__ float    s_red[4][4];        // [wave][{obj,coord,cls,noobj}]

    if (tid < TPB / 32) s_bits[tid] = 0u;
    __syncthreads();

    // mark occupied cells of image b that fall in this block's chunk
    if (tid < NT) {
        const float* tp = tgt + ((size_t)b * NT + tid) * 5;
        const int tx = (int)(tp[1] * GRID_SZ);    // unclipped, as in reference
        const int ty = (int)(tp[2] * GRID_SZ);
        const int ci = ty * GRID_SZ + tx - blk * TPB;
        if ((unsigned)ci < TPB) atomicOr(&s_bits[ci >> 5], 1u << (ci & 31));
    }

    // ---- target losses: waves 0,1 each own target 2*blockIdx + w (3200 total) ----
    float obj = 0.f, coord = 0.f, cls = 0.f;
    if (w < 2) {
        const int gt = blockIdx.x * 2 + w;         // 0..3199
        const int tb = gt / NT, tt = gt - tb * NT;
        const float* tp = tgt + ((size_t)tb * NT + tt) * 5;
        const float t0 = tp[0], t1 = tp[1], t2 = tp[2], t3 = tp[3], t4 = tp[4];
        const int   cid = (int)t0;                 // already floored by setup
        const float xg = t1 * GRID_SZ, yg = t2 * GRID_SZ;
        const float wg = t3 * GRID_SZ, hg = t4 * GRID_SZ;
        const int gx = min(max((int)xg, 0), GRID_SZ - 1);
        const int gy = min(max((int)yg, 0), GRID_SZ - 1);
        const float xt = xg - (float)gx;
        const float yt = yg - (float)gy;
        const float* pp = pred + (((size_t)tb * GRID_SZ + gy) * GRID_SZ + gx) * C5;

        {   // channel = lane (0..63), contiguous -> coalesced
            const float p = pp[lane];
            if (lane == 0)      obj = sp(-p);
            else if (lane == 1) { const float s = 1.f / (1.f + expf(-p)); const float d = s - xt; coord = d * d; }
            else if (lane == 2) { const float s = 1.f / (1.f + expf(-p)); const float d = s - yt; coord = d * d; }
            else if (lane == 3) { const float d = p - wg; coord = d * d; }
            else if (lane == 4) { const float d = p - hg; coord = d * d; }
            else                cls = sp(p) - ((lane - 5) == cid ? p : 0.f);
        }
        const int c2 = lane + 64;                  // channels 64..84
        if (c2 < C5) {
            const float p = pp[c2];
            cls += sp(p) - ((c2 - 5) == cid ? p : 0.f);
        }
    }

    // ---- noobj: one cell per thread ----
    __syncthreads();                               // bitmap ready
    const int ci = blk * TPB + tid;                // cell index within image
    const float p0 = pred[((size_t)b * CELLS + ci) * C5];
    const bool occ = (s_bits[tid >> 5] >> (tid & 31)) & 1u;
    float nob = occ ? 0.f : sp(p0);

    // wave reduce all 4 partials
    #pragma unroll
    for (int off = 32; off; off >>= 1) {
        obj   += __shfl_xor(obj,   off);
        coord += __shfl_xor(coord, off);
        cls   += __shfl_xor(cls,   off);
        nob   += __shfl_xor(nob,   off);
    }
    if (lane == 0) { s_red[w][0] = obj; s_red[w][1] = coord; s_red[w][2] = cls; s_red[w][3] = nob; }
    __syncthreads();
    if (tid < 4) {
        const float v = s_red[0][tid] + s_red[1][tid] + s_red[2][tid] + s_red[3][tid];
        partials[(size_t)blockIdx.x * 4 + tid] = v;   // unconditional write, no init needed
    }
}

__global__ __launch_bounds__(TPB) void finalize_kernel(const float* __restrict__ partials,
                                                       float* __restrict__ out) {
    const int tid = threadIdx.x;
    float o = 0.f, c = 0.f, k = 0.f, n = 0.f;
    const float4* p4 = (const float4*)partials;
    for (int b = tid; b < NBLK; b += TPB) {        // each block's 4 floats = one float4
        const float4 v = p4[b];
        o += v.x; c += v.y; k += v.z; n += v.w;
    }
    #pragma unroll
    for (int off = 32; off; off >>= 1) {
        o += __shfl_xor(o, off);
        c += __shfl_xor(c, off);
        k += __shfl_xor(k, off);
        n += __shfl_xor(n, off);
    }
    __shared__ float s[4][4];
    const int lane = tid & 63, w = tid >> 6;
    if (lane == 0) { s[w][0] = o; s[w][1] = c; s[w][2] = k; s[w][3] = n; }
    __syncthreads();
    if (tid == 0) {
        float obj = 0.f, coord = 0.f, cls = 0.f, nob = 0.f;
        #pragma unroll
        for (int i = 0; i < 4; ++i) { obj += s[i][0]; coord += s[i][1]; cls += s[i][2]; nob += s[i][3]; }
        const float invB = 1.f / (float)BATCH;
        obj   = obj * invB;
        coord = 5.0f * coord * invB;
        cls   = cls * invB;
        nob   = 0.5f * nob * invB;
        out[0] = obj + nob + coord + cls;
        out[1] = obj;
        out[2] = nob;
        out[3] = coord;
        out[4] = cls;
    }
}

extern "C" void kernel_launch(void* const* d_in, const int* in_sizes, int n_in,
                              void* d_out, int out_size, void* d_ws, size_t ws_size,
                              hipStream_t stream) {
    const float* pred = (const float*)d_in[0];
    const float* tgt  = (const float*)d_in[1];
    float* partials = (float*)d_ws;
    float* out      = (float*)d_out;

    main_kernel<<<NBLK, TPB, 0, stream>>>(pred, tgt, partials);
    finalize_kernel<<<1, TPB, 0, stream>>>(partials, out);
}